// Round 2
// baseline (195.769 us; speedup 1.0000x reference)
//
#include <hip/hip_runtime.h>

#define AS1 __attribute__((address_space(1)))
#define AS3 __attribute__((address_space(3)))

typedef _Float16 half_t;
typedef __attribute__((ext_vector_type(8))) _Float16 f16x8;  // 8 f16 = 4 VGPRs
typedef __attribute__((ext_vector_type(4))) float f32x4;

static constexpr int Bsz = 4096;   // batch
static constexpr int INs = 512;    // input features
static constexpr int Hs  = 1024;   // hidden
static constexpr int BK  = 64;     // K-tile
static constexpr int NIT = INs / BK + Hs / BK;   // 8 + 16 = 24 K-steps

// 8-phase 256x256 tile (T3+T4 structure)
static constexpr int BM  = 256;    // batch rows per block
static constexpr int BHh = 64;     // h-cols per block (x4 gates = 256 eff cols)

static constexpr size_t XN  = (size_t)Bsz * INs;
static constexpr size_t HXN = (size_t)Bsz * Hs;
static constexpr size_t WXN = (size_t)4 * Hs * INs;
static constexpr size_t WHN = (size_t)4 * Hs * Hs;
static constexpr size_t OFF_X  = 0;
static constexpr size_t OFF_HX = XN;
static constexpr size_t OFF_WX = XN + HXN;
static constexpr size_t OFF_WH = XN + HXN + WXN;
static constexpr size_t TOT    = XN + HXN + WXN + WHN;   // 12,582,912 f16

__device__ __forceinline__ float sigm(float x) {
  return 1.0f / (1.0f + __expf(-x));
}
__device__ __forceinline__ float tanh_fast(float x) {
  const float e = __expf(2.0f * x);
  return 1.0f - 2.0f / (e + 1.0f);
}

// fp32 -> fp16 (RNE) of the four matmul operands into ws. Loop-free;
// grid covers TOT/8 chunks exactly.
__global__ __launch_bounds__(256)
void cvt_kernel(const float* __restrict__ x, const float* __restrict__ hx,
                const float* __restrict__ wx, const float* __restrict__ wh,
                half_t* __restrict__ ws) {
  const size_t cid = (size_t)blockIdx.x * 256 + threadIdx.x;
  const size_t e = cid * 8;
  const float* src; size_t off;
  if (e < OFF_HX)      { src = x;  off = e - OFF_X; }
  else if (e < OFF_WX) { src = hx; off = e - OFF_HX; }
  else if (e < OFF_WH) { src = wx; off = e - OFF_WX; }
  else                 { src = wh; off = e - OFF_WH; }
  const f32x4 a = *(const f32x4*)(src + off);
  const f32x4 b = *(const f32x4*)(src + off + 4);
  f16x8 o;
  o[0]=(half_t)a[0]; o[1]=(half_t)a[1]; o[2]=(half_t)a[2]; o[3]=(half_t)a[3];
  o[4]=(half_t)b[0]; o[5]=(half_t)b[1]; o[6]=(half_t)b[2]; o[7]=(half_t)b[3];
  *(f16x8*)(ws + e) = o;
}

struct KS { const half_t* A; const half_t* W; int Ka; int k0; };

// ---------------------------------------------------------------------------
// 256x256 8-phase GEMM (m201 template, r1-fixed):
//  - NO sched_barrier(0) (m141: order-pinning regressed 874->510 TF; our
//    ds_reads are compiler-visible, rule-18 does not apply)
//  - a0 kept live P1..P4 (no re-read; P4/P8 are zero-read phases)
//  - vmcnt(6) (m201 constant; liveness re-verified: P4-end 20 issued ->
//    #13-14 landed for P5; P8-end 28 issued -> #17-22 landed for next P1)
//  - lgkmcnt(8) pre-barrier hint on the 12-read phases (P1/P5)
// 512 threads = 8 waves as 2M x 4N; per-wave 128 rows x 64 eff-cols.
// K-steps: t=0..7 -> x@WxhT (Ka=512), t=8..23 -> hx@WhhT.
// LDS 128 KB As[2]/Bs[2]; XOR-swizzled 16B-chunk layout (0 conflicts).
// Phase schedule per iteration (t0=2i):
//   P1 Q(m0,n0)@s0  reads a0,b0 (12)  stage As1.h0 <- t0+1   [lgkm8 hint]
//   P2 Q(m1,n0)@s0  reads a1 (8)      stage Bs1.h1 <- t0+1
//   P3 Q(m1,n1)@s0  reads b1 (4)      stage Bs0.h0 <- t0+2
//   P4 Q(m0,n1)@s0  reads none        stage As0.h1 <- t0+2   vmcnt(6)
//   P5..P8 same on slot1 with t0+2/t0+3 stages.
// ---------------------------------------------------------------------------

#define STAGE_A(dst, s, mh) do { \
  _Pragma("unroll") \
  for (int rr = 0; rr < 2; ++rr) { \
    const int e_ = rr * 128 + (mh) * 64 + j; \
    const int gc8_ = ldc ^ (e_ & 7); \
    const half_t* ga_ = (s).A + (size_t)(m0 + e_) * (s).Ka + ((s).k0 + gc8_ * 8); \
    __builtin_amdgcn_global_load_lds((AS1 void*)ga_, \
        (AS3 void*)((dst) + (e_ * 8 + ldc) * 8), 16, 0, 0); \
  } } while (0)

#define STAGE_B(dst, s, nh) do { \
  _Pragma("unroll") \
  for (int rr = 0; rr < 2; ++rr) { \
    const int e_ = rr * 128 + ((j >> 5) << 6) + (nh) * 32 + (j & 31); \
    const int gc8_ = ldc ^ (e_ & 7); \
    const int wrow_ = ((e_ >> 4) & 3) * Hs + h0 + ((e_ >> 6) << 4) + (e_ & 15); \
    const half_t* gw_ = (s).W + (size_t)wrow_ * (s).Ka + ((s).k0 + gc8_ * 8); \
    __builtin_amdgcn_global_load_lds((AS1 void*)gw_, \
        (AS3 void*)((dst) + (e_ * 8 + ldc) * 8), 16, 0, 0); \
  } } while (0)

#define READ_A(d, base, mh) do { \
  _Pragma("unroll") \
  for (int m_ = 0; m_ < 4; ++m_) { \
    const int e_ = wr * 128 + (mh) * 64 + m_ * 16 + l15; \
    _Pragma("unroll") \
    for (int kk_ = 0; kk_ < 2; ++kk_) \
      d[m_][kk_] = *(const f16x8*)((base) + (e_ * 8 + ((kk_ * 4 + grp) ^ (l15 & 7))) * 8); \
  } } while (0)

#define READ_B(d, base, nh) do { \
  _Pragma("unroll") \
  for (int n_ = 0; n_ < 2; ++n_) { \
    const int e_ = wcn * 64 + (nh) * 32 + n_ * 16 + l15; \
    _Pragma("unroll") \
    for (int kk_ = 0; kk_ < 2; ++kk_) \
      d[n_][kk_] = *(const f16x8*)((base) + (e_ * 8 + ((kk_ * 4 + grp) ^ (l15 & 7))) * 8); \
  } } while (0)

#define QUAD(mh, nh, A_, B_) do { \
  _Pragma("unroll") \
  for (int m_ = 0; m_ < 4; ++m_) \
    _Pragma("unroll") \
    for (int n_ = 0; n_ < 2; ++n_) \
      _Pragma("unroll") \
      for (int kk_ = 0; kk_ < 2; ++kk_) \
        acc[(mh) * 4 + m_][(nh) * 2 + n_] = __builtin_amdgcn_mfma_f32_16x16x32_f16( \
            A_[m_][kk_], B_[n_][kk_], acc[(mh) * 4 + m_][(nh) * 2 + n_], 0, 0, 0); \
  } while (0)

// phase brackets (NO sched_barrier -- let the compiler schedule; it tracks
// the ds_read register deps itself and emits fine-grained lgkmcnt)
#define PH_BAR() do { \
  __builtin_amdgcn_s_barrier(); \
  asm volatile("s_waitcnt lgkmcnt(0)" ::: "memory"); \
  __builtin_amdgcn_s_setprio(1); } while (0)

#define PH_BAR_H() do { \
  asm volatile("s_waitcnt lgkmcnt(8)" ::: "memory"); \
  __builtin_amdgcn_s_barrier(); \
  asm volatile("s_waitcnt lgkmcnt(0)" ::: "memory"); \
  __builtin_amdgcn_s_setprio(1); } while (0)

#define PH_DONE() do { \
  __builtin_amdgcn_s_setprio(0); \
  __builtin_amdgcn_s_barrier(); } while (0)

#define PH_DONE_VM() do { \
  __builtin_amdgcn_s_setprio(0); \
  asm volatile("s_waitcnt vmcnt(6)" ::: "memory"); \
  __builtin_amdgcn_s_barrier(); } while (0)

__global__ __launch_bounds__(512, 2)
void plstm_gemm(const half_t* __restrict__ xin,   // [B,IN]  f16
                const half_t* __restrict__ hxp,   // [B,H]   f16
                const float* __restrict__ cxp,    // [B,H]
                const half_t* __restrict__ wxh,   // [4H,IN] f16
                const float* __restrict__ biasp,  // [4H]
                const half_t* __restrict__ whh,   // [4H,H]  f16
                const float* __restrict__ timep,  // [B]
                const float* __restrict__ taup,   // [H]
                const float* __restrict__ sp,     // [H]
                const float* __restrict__ alphap, // [1]
                const float* __restrict__ rhop,   // [1]
                float* __restrict__ outp)         // [2,B,H] = hy ; cy
{
  __shared__ half_t As[2][BM * BK];   // 2 x 32 KB
  __shared__ half_t Bs[2][BM * BK];   // 2 x 32 KB

  const int tid  = threadIdx.x;
  const int w    = tid >> 6;
  const int lane = tid & 63;
  const int l15  = lane & 15;
  const int grp  = lane >> 4;
  const int wr   = w >> 2;           // 0..1 (m)
  const int wcn  = w & 3;            // 0..3 (n)

  const int m0 = blockIdx.x * BM;
  const int h0 = blockIdx.y * BHh;

  const int j   = tid >> 3;          // 0..63 staging row-in-round
  const int ldc = tid & 7;           // 16B chunk col

  f32x4 acc[8][4] = {};              // [m-subtile][gate]
  f16x8 a0[4][2], a1[4][2], b0[2][2], b1[2][2];

  auto ks = [&](int t) -> KS {
    if (t >= NIT) t -= NIT;          // tail wrap: keeps vmcnt counting uniform
    KS r;
    if (t < INs / BK) { r.A = xin; r.W = wxh; r.Ka = INs; r.k0 = t * BK; }
    else              { r.A = hxp; r.W = whh; r.Ka = Hs;  r.k0 = (t - INs / BK) * BK; }
    return r;
  };

  // ---- prologue: tile0 fully -> slot0; tile1 {B.h0, A.h1} -> slot1 ----
  {
    const KS s0 = ks(0), s1 = ks(1);
    STAGE_A(As[0], s0, 0); STAGE_A(As[0], s0, 1);
    STAGE_B(Bs[0], s0, 0); STAGE_B(Bs[0], s0, 1);
    STAGE_B(Bs[1], s1, 0); STAGE_A(As[1], s1, 1);
    asm volatile("s_waitcnt vmcnt(4)" ::: "memory");   // tile0's 8 loads landed
    __builtin_amdgcn_s_barrier();
  }

  #pragma unroll 1
  for (int i = 0; i < NIT / 2; ++i) {
    const int t0 = 2 * i;
    const KS k1 = ks(t0 + 1), k2 = ks(t0 + 2), k3 = ks(t0 + 3);

    // P1: Q(m0,n0) of tile t0 (slot0) -- 12 reads
    READ_A(a0, As[0], 0); READ_B(b0, Bs[0], 0);
    STAGE_A(As[1], k1, 0);
    PH_BAR_H(); QUAD(0, 0, a0, b0); PH_DONE();
    // P2: Q(m1,n0) -- 8 reads
    READ_A(a1, As[0], 1);
    STAGE_B(Bs[1], k1, 1);
    PH_BAR(); QUAD(1, 0, a1, b0); PH_DONE();
    // P3: Q(m1,n1) -- 4 reads
    READ_B(b1, Bs[0], 1);
    STAGE_B(Bs[0], k2, 0);
    PH_BAR(); QUAD(1, 1, a1, b1); PH_DONE();
    // P4: Q(m0,n1) -- 0 reads (a0 kept live from P1)
    STAGE_A(As[0], k2, 1);
    PH_BAR(); QUAD(0, 1, a0, b1); PH_DONE_VM();

    // P5: Q(m0,n0) of tile t0+1 (slot1) -- 12 reads
    READ_A(a0, As[1], 0); READ_B(b0, Bs[1], 0);
    STAGE_A(As[0], k2, 0);
    PH_BAR_H(); QUAD(0, 0, a0, b0); PH_DONE();
    // P6: Q(m1,n0) -- 8 reads
    READ_A(a1, As[1], 1);
    STAGE_B(Bs[0], k2, 1);
    PH_BAR(); QUAD(1, 0, a1, b0); PH_DONE();
    // P7: Q(m1,n1) -- 4 reads
    READ_B(b1, Bs[1], 1);
    STAGE_B(Bs[1], k3, 0);
    PH_BAR(); QUAD(1, 1, a1, b1); PH_DONE();
    // P8: Q(m0,n1) -- 0 reads
    STAGE_A(As[1], k3, 1);
    PH_BAR(); QUAD(0, 1, a0, b1); PH_DONE_VM();
  }

  // ---- fused epilogue: each lane owns ONE h (all 4 gates) and 32 rows ----
  const int h = h0 + wcn * 16 + l15;
  const float bi  = biasp[h];
  const float bfv = biasp[Hs + h];
  const float bg  = biasp[2 * Hs + h];
  const float bo  = biasp[3 * Hs + h];
  const float sv = sp[h], tauv = taup[h];
  const float alphav = alphap[0], rhov = rhop[0], rh = 0.5f * rhov;

  #pragma unroll
  for (int mt = 0; mt < 8; ++mt) {
    #pragma unroll
    for (int r = 0; r < 4; ++r) {
      // C/D layout (m89-verified): col = lane&15, row = grp*4 + reg
      const int brow = m0 + wr * 128 + mt * 16 + grp * 4 + r;
      const float tv = timep[brow];
      const float phi = fmodf(tv - sv, tauv) / tauv;
      float kv;
      if (phi < rh)        kv = (2.0f * phi) / rhov;
      else if (phi < rhov) kv = 2.0f - (2.0f * phi) / rhov;
      else                 kv = alphav * phi;

      const float iv = acc[mt][0][r] + bi;
      const float fv = acc[mt][1][r] + bfv;
      const float gv = acc[mt][2][r] + bg;
      const float ov = acc[mt][3][r] + bo;
      const float cxv = cxp[(size_t)brow * Hs + h];
      const float ft = sigm(fv + 1.0f - kv);
      const float it2 = sigm(iv) * kv;
      const float gt = tanh_fast(gv) * kv;
      const float ot = sigm(ov) * kv;
      const float cy = ft * cxv + it2 * gt;
      const float hy = ot * tanh_fast(cy);

      outp[(size_t)brow * Hs + h] = hy;
      outp[(size_t)Bsz * Hs + (size_t)brow * Hs + h] = cy;
    }
  }
}

// Fallback (no usable ws): 128x128 single kernel, fp32 converted during
// staging. Unchanged (grid 32x32, 256 threads).
__global__ __launch_bounds__(256, 3)
void plstm_gemm_f32(const float* __restrict__ xin, const float* __restrict__ timep,
                    const float* __restrict__ hxp, const float* __restrict__ cxp,
                    const float* __restrict__ wxh, const float* __restrict__ biasp,
                    const float* __restrict__ whh, const float* __restrict__ taup,
                    const float* __restrict__ sp, const float* __restrict__ alphap,
                    const float* __restrict__ rhop, float* __restrict__ outp)
{
  __shared__ half_t Asf[128 * BK];
  __shared__ half_t Bsf[128 * BK];

  const int tid  = threadIdx.x;
  const int w    = tid >> 6;
  const int lane = tid & 63;
  const int l15  = lane & 15;
  const int grp  = lane >> 4;
  const int wrl  = w >> 1;
  const int wcl  = w & 1;

  const int m0 = blockIdx.x * 128;
  const int h0 = blockIdx.y * 32;

  f32x4 acc[4][4] = {};
  const int ldr = tid >> 3;
  const int ldc = tid & 7;

  for (int it = 0; it < NIT; ++it) {
    const bool p1 = it >= INs / BK;
    const float* Ap = p1 ? hxp : xin;
    const float* Wp = p1 ? whh : wxh;
    const int Ka = p1 ? Hs : INs;
    const int k0 = (p1 ? (it - INs / BK) : it) * BK;
    #pragma unroll
    for (int i = 0; i < 4; ++i) {
      const int e    = i * 32 + ldr;
      const int gc8  = ldc ^ (e & 7);
      const int wrow = ((e >> 4) & 3) * Hs + h0 + ((e >> 6) << 4) + (e & 15);
      const float* ga = Ap + (size_t)(m0 + e) * Ka + (k0 + gc8 * 8);
      const f32x4 a0v = *(const f32x4*)ga, a1v = *(const f32x4*)(ga + 4);
      f16x8 pa;
      pa[0]=(half_t)a0v[0]; pa[1]=(half_t)a0v[1]; pa[2]=(half_t)a0v[2]; pa[3]=(half_t)a0v[3];
      pa[4]=(half_t)a1v[0]; pa[5]=(half_t)a1v[1]; pa[6]=(half_t)a1v[2]; pa[7]=(half_t)a1v[3];
      *(f16x8*)(Asf + (e * 8 + ldc) * 8) = pa;
      const float* gw = Wp + (size_t)wrow * Ka + (k0 + gc8 * 8);
      const f32x4 b0v = *(const f32x4*)gw, b1v = *(const f32x4*)(gw + 4);
      f16x8 pb;
      pb[0]=(half_t)b0v[0]; pb[1]=(half_t)b0v[1]; pb[2]=(half_t)b0v[2]; pb[3]=(half_t)b0v[3];
      pb[4]=(half_t)b1v[0]; pb[5]=(half_t)b1v[1]; pb[6]=(half_t)b1v[2]; pb[7]=(half_t)b1v[3];
      *(f16x8*)(Bsf + (e * 8 + ldc) * 8) = pb;
    }
    __syncthreads();
    #pragma unroll
    for (int kk = 0; kk < 2; ++kk) {
      const int c8x = kk * 4 + grp;
      f16x8 af[4], bfr[4];
      #pragma unroll
      for (int mt = 0; mt < 4; ++mt) {
        const int e = wrl * 64 + mt * 16 + l15;
        af[mt] = *(const f16x8*)(Asf + (e * 8 + (c8x ^ (l15 & 7))) * 8);
      }
      #pragma unroll
      for (int nt = 0; nt < 4; ++nt) {
        const int e = wcl * 64 + nt * 16 + l15;
        bfr[nt] = *(const f16x8*)(Bsf + (e * 8 + (c8x ^ (l15 & 7))) * 8);
      }
      #pragma unroll
      for (int mt = 0; mt < 4; ++mt)
        #pragma unroll
        for (int nt = 0; nt < 4; ++nt)
          acc[mt][nt] = __builtin_amdgcn_mfma_f32_16x16x32_f16(
              af[mt], bfr[nt], acc[mt][nt], 0, 0, 0);
    }
    __syncthreads();
  }

  const int h = h0 + wcl * 16 + l15;
  const float bi  = biasp[h];
  const float bfv = biasp[Hs + h];
  const float bg  = biasp[2 * Hs + h];
  const float bo  = biasp[3 * Hs + h];
  const float sv = sp[h], tauv = taup[h];
  const float alphav = alphap[0], rhov = rhop[0], rh = 0.5f * rhov;

  #pragma unroll
  for (int mt = 0; mt < 4; ++mt) {
    #pragma unroll
    for (int r = 0; r < 4; ++r) {
      const int brow = m0 + wrl * 64 + mt * 16 + grp * 4 + r;
      const float tv = timep[brow];
      const float phi = fmodf(tv - sv, tauv) / tauv;
      float kv;
      if (phi < rh)        kv = (2.0f * phi) / rhov;
      else if (phi < rhov) kv = 2.0f - (2.0f * phi) / rhov;
      else                 kv = alphav * phi;
      const float iv = acc[mt][0][r] + bi;
      const float fv = acc[mt][1][r] + bfv;
      const float gv = acc[mt][2][r] + bg;
      const float ov = acc[mt][3][r] + bo;
      const float cxv = cxp[(size_t)brow * Hs + h];
      const float ft = sigm(fv + 1.0f - kv);
      const float it2 = sigm(iv) * kv;
      const float gt = tanh_fast(gv) * kv;
      const float ot = sigm(ov) * kv;
      const float cy = ft * cxv + it2 * gt;
      const float hy = ot * tanh_fast(cy);
      outp[(size_t)brow * Hs + h] = hy;
      outp[(size_t)Bsz * Hs + (size_t)brow * Hs + h] = cy;
    }
  }
}

extern "C" void kernel_launch(void* const* d_in, const int* in_sizes, int n_in,
                              void* d_out, int out_size, void* d_ws, size_t ws_size,
                              hipStream_t stream) {
  (void)in_sizes; (void)n_in; (void)out_size;
  const float* xin   = (const float*)d_in[0];
  const float* timep = (const float*)d_in[1];
  const float* hxp   = (const float*)d_in[2];
  const float* cxp   = (const float*)d_in[3];
  const float* wxh   = (const float*)d_in[4];
  const float* biasp = (const float*)d_in[5];
  const float* whh   = (const float*)d_in[6];
  const float* taup  = (const float*)d_in[7];
  const float* sp    = (const float*)d_in[8];
  const float* alphap= (const float*)d_in[9];
  const float* rhop  = (const float*)d_in[10];
  float* outp = (float*)d_out;

  if (ws_size >= TOT * sizeof(half_t)) {
    half_t* ws = (half_t*)d_ws;
    cvt_kernel<<<(int)(TOT / 8 / 256), 256, 0, stream>>>(xin, hxp, wxh, whh, ws);
    dim3 grid(Bsz / BM, Hs / BHh);   // 16 x 16 = 256 blocks = 1 per CU
    plstm_gemm<<<grid, 512, 0, stream>>>(
        ws + OFF_X, ws + OFF_HX, cxp, ws + OFF_WX, biasp, ws + OFF_WH,
        timep, taup, sp, alphap, rhop, outp);
  } else {
    dim3 fgrid(Bsz / 128, Hs / 32);
    plstm_gemm_f32<<<fgrid, 256, 0, stream>>>(
        xin, timep, hxp, cxp, wxh, biasp, whh,
        taup, sp, alphap, rhop, outp);
  }
}

// Round 3
// 180.830 us; speedup vs baseline: 1.0826x; 1.0826x over previous
//
#include <hip/hip_runtime.h>

#define AS1 __attribute__((address_space(1)))
#define AS3 __attribute__((address_space(3)))

typedef _Float16 half_t;
typedef __attribute__((ext_vector_type(8))) _Float16 f16x8;  // 8 f16 = 4 VGPRs
typedef __attribute__((ext_vector_type(4))) float f32x4;

static constexpr int Bsz = 4096;   // batch
static constexpr int INs = 512;    // input features
static constexpr int Hs  = 1024;   // hidden
static constexpr int BM  = 128;    // batch rows per block
static constexpr int BH  = 32;     // h-cols per block (x4 gates = 128 eff cols)
static constexpr int BK  = 64;     // K-tile

static constexpr size_t XN  = (size_t)Bsz * INs;
static constexpr size_t HXN = (size_t)Bsz * Hs;
static constexpr size_t WXN = (size_t)4 * Hs * INs;
static constexpr size_t WHN = (size_t)4 * Hs * Hs;
static constexpr size_t OFF_X  = 0;
static constexpr size_t OFF_HX = XN;
static constexpr size_t OFF_WX = XN + HXN;
static constexpr size_t OFF_WH = XN + HXN + WXN;
static constexpr size_t TOT    = XN + HXN + WXN + WHN;   // 12,582,912 f16

__device__ __forceinline__ float sigm(float x) {
  return 1.0f / (1.0f + __expf(-x));
}
__device__ __forceinline__ float tanh_fast(float x) {
  const float e = __expf(2.0f * x);
  return 1.0f - 2.0f / (e + 1.0f);
}

// fp32 -> fp16 (RNE) of the four matmul operands into ws. Loop-free;
// grid covers TOT/8 chunks exactly.
__global__ __launch_bounds__(256)
void cvt_kernel(const float* __restrict__ x, const float* __restrict__ hx,
                const float* __restrict__ wx, const float* __restrict__ wh,
                half_t* __restrict__ ws) {
  const size_t cid = (size_t)blockIdx.x * 256 + threadIdx.x;
  const size_t e = cid * 8;
  const float* src; size_t off;
  if (e < OFF_HX)      { src = x;  off = e - OFF_X; }
  else if (e < OFF_WX) { src = hx; off = e - OFF_HX; }
  else if (e < OFF_WH) { src = wx; off = e - OFF_WX; }
  else                 { src = wh; off = e - OFF_WH; }
  const f32x4 a = *(const f32x4*)(src + off);
  const f32x4 b = *(const f32x4*)(src + off + 4);
  f16x8 o;
  o[0]=(half_t)a[0]; o[1]=(half_t)a[1]; o[2]=(half_t)a[2]; o[3]=(half_t)a[3];
  o[4]=(half_t)b[0]; o[5]=(half_t)b[1]; o[6]=(half_t)b[2]; o[7]=(half_t)b[3];
  *(f16x8*)(ws + e) = o;
}

// ---------------------------------------------------------------------------
// r0-proven 128x128 GEMM structure (4 blocks/CU co-resident, 32 KB LDS,
// cross-block wave overlap fills barrier stalls), with r3's VALU reduction:
//  - K-loop split into two fully-unrolled phase loops (x@WxhT: 8 steps,
//    hx@WhhT: 16 steps). All staging addresses decompose into
//    {uniform base} + {per-lane int, loop-invariant} + {compile-time const}:
//    zero per-step address VALU (was: per-step phase-select + 8x 64-bit mul).
//  - Epilogue: fmodf + per-row divides replaced by rtau=1/tau, tworho=2/rho
//    (hoisted) and phi = q - trunc(q), q = (t-s)*rtau  — identical to
//    fmod(t-s,tau)/tau in exact arithmetic, ~8 cheap VALU/row vs ~45.
// MFMA inner loop, XOR-swizzled LDS layout (0 measured conflicts), barrier
// placement: byte-identical to the r0 kernel.
// Wave tiling 2x2: wave (wr,wc) -> rows wr*64+mt*16, eff-cols wc*64+nt*16.
// Eff-col c -> gate (c>>4)&3, h = h0 + (c>>6)*16 + (c&15): all four gates of
// one (b,h) sit in the same lane across acc[mt][0..3].
// ---------------------------------------------------------------------------

#define KSTEP(Abase, vA, Wbase, vB, Ka_, t_) do { \
  _Pragma("unroll") \
  for (int i_ = 0; i_ < 4; ++i_) { \
    const int e_ = i_ * 32 + ldr; \
    const half_t* ga_ = (Abase) + (vA) + (i_ * 32 * (Ka_) + (t_) * BK); \
    __builtin_amdgcn_global_load_lds((AS1 void*)ga_, \
        (AS3 void*)(As + (e_ * 8 + ldc) * 8), 16, 0, 0); \
    const half_t* gw_ = (Wbase) + (vB)[i_] + ((t_) * BK); \
    __builtin_amdgcn_global_load_lds((AS1 void*)gw_, \
        (AS3 void*)(Bs + (e_ * 8 + ldc) * 8), 16, 0, 0); \
  } \
  __syncthreads(); \
  _Pragma("unroll") \
  for (int kk_ = 0; kk_ < 2; ++kk_) { \
    const int c8x_ = kk_ * 4 + grp; \
    f16x8 af_[4], bf_[4]; \
    _Pragma("unroll") \
    for (int mt_ = 0; mt_ < 4; ++mt_) { \
      const int e_ = wr * 64 + mt_ * 16 + l15; \
      af_[mt_] = *(const f16x8*)(As + (e_ * 8 + (c8x_ ^ (l15 & 7))) * 8); \
    } \
    _Pragma("unroll") \
    for (int nt_ = 0; nt_ < 4; ++nt_) { \
      const int e_ = wc * 64 + nt_ * 16 + l15; \
      bf_[nt_] = *(const f16x8*)(Bs + (e_ * 8 + (c8x_ ^ (l15 & 7))) * 8); \
    } \
    _Pragma("unroll") \
    for (int mt_ = 0; mt_ < 4; ++mt_) \
      _Pragma("unroll") \
      for (int nt_ = 0; nt_ < 4; ++nt_) \
        acc[mt_][nt_] = __builtin_amdgcn_mfma_f32_16x16x32_f16( \
            af_[mt_], bf_[nt_], acc[mt_][nt_], 0, 0, 0); \
  } \
  __syncthreads(); \
} while (0)

__global__ __launch_bounds__(256, 4)
void plstm_gemm(const half_t* __restrict__ xin,   // [B,IN]  f16
                const half_t* __restrict__ hxp,   // [B,H]   f16
                const float* __restrict__ cxp,    // [B,H]
                const half_t* __restrict__ wxh,   // [4H,IN] f16
                const float* __restrict__ biasp,  // [4H]
                const half_t* __restrict__ whh,   // [4H,H]  f16
                const float* __restrict__ timep,  // [B]
                const float* __restrict__ taup,   // [H]
                const float* __restrict__ sp,     // [H]
                const float* __restrict__ alphap, // [1]
                const float* __restrict__ rhop,   // [1]
                float* __restrict__ outp)         // [2,B,H] = hy ; cy
{
  // XOR-swizzled 16B-chunk layout: slot (row e, c8) holds global chunk c8^(e&7).
  __shared__ half_t As[BM * BK];    // 16 KB
  __shared__ half_t Bs[BM * BK];    // 16 KB

  const int tid  = threadIdx.x;
  const int w    = tid >> 6;
  const int lane = tid & 63;
  const int l15  = lane & 15;
  const int grp  = lane >> 4;
  const int wr   = w >> 1;
  const int wc   = w & 1;

  const int m0 = blockIdx.x * BM;
  const int h0 = blockIdx.y * BH;

  f32x4 acc[4][4] = {};              // [m-subtile][gate]

  const int ldr = tid >> 3;          // 0..31
  const int ldc = tid & 7;           // 16B chunk col 0..7
  const int gc8 = ldc ^ (ldr & 7);   // global-side swizzle chunk (per-thread const)

  // ---- phase X: x[B,IN] @ WxhT, 8 K-steps, fully unrolled ----
  {
    const half_t* Ab = xin + (size_t)m0 * INs;   // uniform base
    const int vA = ldr * INs + gc8 * 8;          // per-lane, loop-invariant
    int vB[4];
    #pragma unroll
    for (int i = 0; i < 4; ++i) {
      const int gi = (2 * i + (ldr >> 4)) & 3;
      vB[i] = (gi * Hs + h0 + (i >> 1) * 16 + (ldr & 15)) * INs + gc8 * 8;
    }
    #pragma unroll
    for (int t = 0; t < INs / BK; ++t)
      KSTEP(Ab, vA, wxh, vB, INs, t);
  }
  // ---- phase H: hx[B,H] @ WhhT, 16 K-steps, fully unrolled ----
  {
    const half_t* Ab = hxp + (size_t)m0 * Hs;
    const int vA = ldr * Hs + gc8 * 8;
    int vB[4];
    #pragma unroll
    for (int i = 0; i < 4; ++i) {
      const int gi = (2 * i + (ldr >> 4)) & 3;
      vB[i] = (gi * Hs + h0 + (i >> 1) * 16 + (ldr & 15)) * Hs + gc8 * 8;
    }
    #pragma unroll
    for (int t = 0; t < Hs / BK; ++t)
      KSTEP(Ab, vA, whh, vB, Hs, t);
  }

  // ---- fused epilogue: each thread owns ONE h and 16 batch rows ----
  const int h = h0 + wc * 16 + l15;
  const float bi  = biasp[h];
  const float bfv = biasp[Hs + h];
  const float bg  = biasp[2 * Hs + h];
  const float bo  = biasp[3 * Hs + h];
  const float sv = sp[h], tauv = taup[h];
  const float alphav = alphap[0], rhov = rhop[0], rh = 0.5f * rhov;
  const float rtau   = 1.0f / tauv;    // hoisted: one divide
  const float tworho = 2.0f / rhov;    // hoisted: one divide

  #pragma unroll
  for (int mt = 0; mt < 4; ++mt) {
    // 4 rows per (mt): one vector load instead of 4 scalar time loads
    const f32x4 t4 = *(const f32x4*)(timep + m0 + wr * 64 + mt * 16 + grp * 4);
    #pragma unroll
    for (int r = 0; r < 4; ++r) {
      // C/D layout (m89-verified): col = lane&15, row = grp*4 + reg
      const int brow = m0 + wr * 64 + mt * 16 + grp * 4 + r;
      // phi = fmod(tv-s, tau)/tau == q - trunc(q), q = (tv-s)/tau (exact arith)
      const float q   = (t4[r] - sv) * rtau;
      const float phi = q - truncf(q);
      const float kv  = phi < rh   ? phi * tworho
                      : (phi < rhov ? 2.0f - phi * tworho
                                    : alphav * phi);

      const float iv = acc[mt][0][r] + bi;
      const float fv = acc[mt][1][r] + bfv;
      const float gv = acc[mt][2][r] + bg;
      const float ov = acc[mt][3][r] + bo;
      const float cxv = cxp[(size_t)brow * Hs + h];
      const float ft = sigm(fv + 1.0f - kv);
      const float it2 = sigm(iv) * kv;
      const float gt = tanh_fast(gv) * kv;
      const float ot = sigm(ov) * kv;
      const float cy = ft * cxv + it2 * gt;
      const float hy = ot * tanh_fast(cy);

      outp[(size_t)brow * Hs + h] = hy;
      outp[(size_t)Bsz * Hs + (size_t)brow * Hs + h] = cy;
    }
  }
}

// Fallback (no usable ws): single kernel, fp32 converted during staging.
__global__ __launch_bounds__(256, 3)
void plstm_gemm_f32(const float* __restrict__ xin, const float* __restrict__ timep,
                    const float* __restrict__ hxp, const float* __restrict__ cxp,
                    const float* __restrict__ wxh, const float* __restrict__ biasp,
                    const float* __restrict__ whh, const float* __restrict__ taup,
                    const float* __restrict__ sp, const float* __restrict__ alphap,
                    const float* __restrict__ rhop, float* __restrict__ outp)
{
  __shared__ half_t As[BM * BK];
  __shared__ half_t Bs[BM * BK];

  const int tid  = threadIdx.x;
  const int w    = tid >> 6;
  const int lane = tid & 63;
  const int l15  = lane & 15;
  const int grp  = lane >> 4;
  const int wr   = w >> 1;
  const int wc   = w & 1;

  const int m0 = blockIdx.x * BM;
  const int h0 = blockIdx.y * BH;

  f32x4 acc[4][4] = {};
  const int ldr = tid >> 3;
  const int ldc = tid & 7;
  const int NIT = INs / BK + Hs / BK;

  for (int it = 0; it < NIT; ++it) {
    const bool p1 = it >= INs / BK;
    const float* Ap = p1 ? hxp : xin;
    const float* Wp = p1 ? whh : wxh;
    const int Ka = p1 ? Hs : INs;
    const int k0 = (p1 ? (it - INs / BK) : it) * BK;
    #pragma unroll
    for (int i = 0; i < 4; ++i) {
      const int e    = i * 32 + ldr;
      const int gc8  = ldc ^ (e & 7);
      const int wrow = ((e >> 4) & 3) * Hs + h0 + ((e >> 6) << 4) + (e & 15);
      const float* ga = Ap + (size_t)(m0 + e) * Ka + (k0 + gc8 * 8);
      const f32x4 a0v = *(const f32x4*)ga, a1v = *(const f32x4*)(ga + 4);
      f16x8 pa;
      pa[0]=(half_t)a0v[0]; pa[1]=(half_t)a0v[1]; pa[2]=(half_t)a0v[2]; pa[3]=(half_t)a0v[3];
      pa[4]=(half_t)a1v[0]; pa[5]=(half_t)a1v[1]; pa[6]=(half_t)a1v[2]; pa[7]=(half_t)a1v[3];
      *(f16x8*)(As + (e * 8 + ldc) * 8) = pa;
      const float* gw = Wp + (size_t)wrow * Ka + (k0 + gc8 * 8);
      const f32x4 b0v = *(const f32x4*)gw, b1v = *(const f32x4*)(gw + 4);
      f16x8 pb;
      pb[0]=(half_t)b0v[0]; pb[1]=(half_t)b0v[1]; pb[2]=(half_t)b0v[2]; pb[3]=(half_t)b0v[3];
      pb[4]=(half_t)b1v[0]; pb[5]=(half_t)b1v[1]; pb[6]=(half_t)b1v[2]; pb[7]=(half_t)b1v[3];
      *(f16x8*)(Bs + (e * 8 + ldc) * 8) = pb;
    }
    __syncthreads();
    #pragma unroll
    for (int kk = 0; kk < 2; ++kk) {
      const int c8x = kk * 4 + grp;
      f16x8 af[4], bfr[4];
      #pragma unroll
      for (int mt = 0; mt < 4; ++mt) {
        const int e = wr * 64 + mt * 16 + l15;
        af[mt] = *(const f16x8*)(As + (e * 8 + (c8x ^ (l15 & 7))) * 8);
      }
      #pragma unroll
      for (int nt = 0; nt < 4; ++nt) {
        const int e = wc * 64 + nt * 16 + l15;
        bfr[nt] = *(const f16x8*)(Bs + (e * 8 + (c8x ^ (l15 & 7))) * 8);
      }
      #pragma unroll
      for (int mt = 0; mt < 4; ++mt)
        #pragma unroll
        for (int nt = 0; nt < 4; ++nt)
          acc[mt][nt] = __builtin_amdgcn_mfma_f32_16x16x32_f16(
              af[mt], bfr[nt], acc[mt][nt], 0, 0, 0);
    }
    __syncthreads();
  }

  const int h = h0 + wc * 16 + l15;
  const float bi  = biasp[h];
  const float bfv = biasp[Hs + h];
  const float bg  = biasp[2 * Hs + h];
  const float bo  = biasp[3 * Hs + h];
  const float sv = sp[h], tauv = taup[h];
  const float alphav = alphap[0], rhov = rhop[0], rh = 0.5f * rhov;
  const float rtau   = 1.0f / tauv;
  const float tworho = 2.0f / rhov;

  #pragma unroll
  for (int mt = 0; mt < 4; ++mt) {
    const f32x4 t4 = *(const f32x4*)(timep + m0 + wr * 64 + mt * 16 + grp * 4);
    #pragma unroll
    for (int r = 0; r < 4; ++r) {
      const int brow = m0 + wr * 64 + mt * 16 + grp * 4 + r;
      const float q   = (t4[r] - sv) * rtau;
      const float phi = q - truncf(q);
      const float kv  = phi < rh   ? phi * tworho
                      : (phi < rhov ? 2.0f - phi * tworho
                                    : alphav * phi);
      const float iv = acc[mt][0][r] + bi;
      const float fv = acc[mt][1][r] + bfv;
      const float gv = acc[mt][2][r] + bg;
      const float ov = acc[mt][3][r] + bo;
      const float cxv = cxp[(size_t)brow * Hs + h];
      const float ft = sigm(fv + 1.0f - kv);
      const float it2 = sigm(iv) * kv;
      const float gt = tanh_fast(gv) * kv;
      const float ot = sigm(ov) * kv;
      const float cy = ft * cxv + it2 * gt;
      const float hy = ot * tanh_fast(cy);
      outp[(size_t)brow * Hs + h] = hy;
      outp[(size_t)Bsz * Hs + (size_t)brow * Hs + h] = cy;
    }
  }
}

extern "C" void kernel_launch(void* const* d_in, const int* in_sizes, int n_in,
                              void* d_out, int out_size, void* d_ws, size_t ws_size,
                              hipStream_t stream) {
  (void)in_sizes; (void)n_in; (void)out_size;
  const float* xin   = (const float*)d_in[0];
  const float* timep = (const float*)d_in[1];
  const float* hxp   = (const float*)d_in[2];
  const float* cxp   = (const float*)d_in[3];
  const float* wxh   = (const float*)d_in[4];
  const float* biasp = (const float*)d_in[5];
  const float* whh   = (const float*)d_in[6];
  const float* taup  = (const float*)d_in[7];
  const float* sp    = (const float*)d_in[8];
  const float* alphap= (const float*)d_in[9];
  const float* rhop  = (const float*)d_in[10];
  float* outp = (float*)d_out;

  dim3 grid(Bsz / BM, Hs / BH);   // 32 x 32 = 1024 blocks = 4 per CU
  if (ws_size >= TOT * sizeof(half_t)) {
    half_t* ws = (half_t*)d_ws;
    cvt_kernel<<<(int)(TOT / 8 / 256), 256, 0, stream>>>(xin, hxp, wxh, whh, ws);
    plstm_gemm<<<grid, 256, 0, stream>>>(
        ws + OFF_X, ws + OFF_HX, cxp, ws + OFF_WX, biasp, ws + OFF_WH,
        timep, taup, sp, alphap, rhop, outp);
  } else {
    plstm_gemm_f32<<<grid, 256, 0, stream>>>(
        xin, timep, hxp, cxp, wxh, biasp, whh,
        taup, sp, alphap, rhop, outp);
  }
}